// Round 4
// baseline (3031.209 us; speedup 1.0000x reference)
//
#include <hip/hip_runtime.h>

#define DIM    128
#define K      256
#define NPTS   32768
#define NALL   (8*32768)
#define ITERS  10
#define NCHUNK 512            // 64 points per chunk for the stable sort

// numpy pairwise sum of squares, n=128, SSE2 path (the real x86-64 code path):
//   c[j] = sq[j] + sq[8+j] + ... + sq[120+j]  (ascending, j=0..7)
//   v_l  = c_l + c_{l+4}                       (_mm_add_ps(r0, r1))
//   res  = (v0 + v2) + (v1 + v3)               (movehl hsum + add_ss)
__device__ __forceinline__ float np_sumsq128(const float* p, int stride) {
    #pragma clang fp contract(off)
    float c[8];
    #pragma unroll
    for (int j = 0; j < 8; ++j) { float x = p[j*stride]; c[j] = x*x; }
    #pragma unroll
    for (int t = 1; t < 16; ++t)
        #pragma unroll
        for (int j = 0; j < 8; ++j) { float x = p[(8*t+j)*stride]; c[j] = c[j] + x*x; }
    float v0 = c[0] + c[4];
    float v1 = c[1] + c[5];
    float v2 = c[2] + c[6];
    float v3 = c[3] + c[7];
    return (v0 + v2) + (v1 + v3);
}

// ---------------- init: centers = X0[:256] ----------------
__global__ void k_init(const float* __restrict__ x0, float* __restrict__ centers) {
    int i = blockIdx.x * blockDim.x + threadIdx.x;
    if (i < K*DIM) centers[i] = x0[i];
}

// ---------------- assignment: bit-replication of np d2 + argmin ----------------
// d2 = fl(fl(x_sq + c_sq) - fl(2*dot)), dot = ascending-k fp32 FMA chain (BLAS).
// grid 256 blocks x 256 thr; block = 128 points (4 passes x 4 waves x 8 points)
__global__ __launch_bounds__(256, 1) void k_assign(
    const float* __restrict__ x0, const float* __restrict__ centers,
    int* __restrict__ assignv)
{
    __shared__ float cT[DIM][K+4];     // centers transposed, +4 pad
    __shared__ float xT[4][DIM][8];    // per-wave 8-point x tile
    __shared__ float csq[K];
    __shared__ float xsq[4][8];

    const int tid  = threadIdx.x;
    const int lane = tid & 63;
    const int w    = tid >> 6;

    for (int idx = tid; idx < K*DIM; idx += 256) {
        int d = idx & (DIM-1);
        int kk = idx >> 7;
        cT[d][kk] = centers[idx];       // idx == kk*128+d (coalesced)
    }
    __syncthreads();
    csq[tid] = np_sumsq128(&cT[0][tid], K+4);   // thread tid handles center k=tid
    __syncthreads();

    const float4 cs4 = *(const float4*)&csq[4*lane];

    const int block_base = blockIdx.x * 128;
    for (int pass = 0; pass < 4; ++pass) {
        const int base = block_base + pass*32 + w*8;
        #pragma unroll
        for (int j = 0; j < 4; ++j) {
            int f4 = lane + 64*j;
            int p = f4 & 7, dblk = f4 >> 3;
            float4 v = *(const float4*)&x0[(size_t)(base+p)*DIM + 4*dblk];
            xT[w][4*dblk+0][p] = v.x;
            xT[w][4*dblk+1][p] = v.y;
            xT[w][4*dblk+2][p] = v.z;
            xT[w][4*dblk+3][p] = v.w;
        }
        __syncthreads();

        if (lane < 8) xsq[w][lane] = np_sumsq128(&xT[w][0][lane], 8);
        __syncthreads();

        float acc[8][4];
        #pragma unroll
        for (int p = 0; p < 8; ++p)
            #pragma unroll
            for (int j = 0; j < 4; ++j) acc[p][j] = 0.f;

        // ascending-d fp32 FMA chains == BLAS sgemm per-element order
        for (int d = 0; d < DIM; ++d) {
            const float4 c  = *(const float4*)&cT[d][4*lane];
            const float4 xa = *(const float4*)&xT[w][d][0];
            const float4 xb = *(const float4*)&xT[w][d][4];
            const float xs[8] = {xa.x,xa.y,xa.z,xa.w,xb.x,xb.y,xb.z,xb.w};
            const float cc[4] = {c.x,c.y,c.z,c.w};
            #pragma unroll
            for (int p = 0; p < 8; ++p)
                #pragma unroll
                for (int j = 0; j < 4; ++j)
                    acc[p][j] = fmaf(xs[p], cc[j], acc[p][j]);
        }

        #pragma unroll
        for (int p = 0; p < 8; ++p) {
            #pragma clang fp contract(off)
            const float xs_ = xsq[w][p];
            float bv; int bi;
            { float m = 2.f*acc[p][0]; float t = xs_ + cs4.x; bv = t - m; bi = 4*lane; }
            { float m = 2.f*acc[p][1]; float t = xs_ + cs4.y; float v = t - m; if (v < bv) { bv=v; bi=4*lane+1; } }
            { float m = 2.f*acc[p][2]; float t = xs_ + cs4.z; float v = t - m; if (v < bv) { bv=v; bi=4*lane+2; } }
            { float m = 2.f*acc[p][3]; float t = xs_ + cs4.w; float v = t - m; if (v < bv) { bv=v; bi=4*lane+3; } }
            #pragma unroll
            for (int off = 32; off > 0; off >>= 1) {
                float ov = __shfl_xor(bv, off);
                int   oi = __shfl_xor(bi, off);
                if (ov < bv || (ov == bv && oi < bi)) { bv = ov; bi = oi; }
            }
            if (lane == p) assignv[base + p] = bi;   // first-min tie rule == np.argmin
        }
        __syncthreads();
    }
}

// ---------------- stable counting sort: counts per chunk ----------------
__global__ __launch_bounds__(256) void s_count(const int* __restrict__ assignv,
                                               int* __restrict__ counts)
{
    __shared__ int cnt[4][K];
    const int tid = threadIdx.x, lane = tid & 63, w = tid >> 6;
    for (int i = tid; i < 4*K; i += 256) ((int*)cnt)[i] = 0;
    __syncthreads();
    int chunk = blockIdx.x*4 + w;
    int a = assignv[chunk*64 + lane];
    atomicAdd(&cnt[w][a], 1);
    __syncthreads();
    for (int i = tid; i < 4*K; i += 256) {
        int w2 = i >> 8, k = i & 255;
        counts[(size_t)(blockIdx.x*4 + w2)*K + k] = cnt[w2][k];
    }
}

// ---------------- offsets: per-(chunk,k) absolute start positions ----------------
__global__ void s_offset(const int* __restrict__ counts, int* __restrict__ chunkoff,
                         int* __restrict__ startk, int* __restrict__ cntk,
                         float* __restrict__ cntf)
{
    __shared__ int tot[K], base[K];
    const int k = threadIdx.x;
    int running = 0;
    for (int ci = 0; ci < NCHUNK; ++ci) {
        chunkoff[(size_t)ci*K + k] = running;
        running += counts[(size_t)ci*K + k];
    }
    tot[k] = running;
    __syncthreads();
    if (k == 0) {
        int acc = 0;
        for (int i = 0; i < K; ++i) { base[i] = acc; acc += tot[i]; }
    }
    __syncthreads();
    const int b = base[k];
    for (int ci = 0; ci < NCHUNK; ++ci) chunkoff[(size_t)ci*K + k] += b;
    startk[k] = b;
    cntk[k]   = tot[k];
    cntf[k]   = (float)tot[k];
}

// ---------------- stable scatter: order[] = point indices grouped by cluster, ascending n ----------------
__global__ __launch_bounds__(256) void s_scatter(const int* __restrict__ assignv,
        const int* __restrict__ chunkoff, int* __restrict__ order)
{
    __shared__ int ids[4][64];
    const int tid = threadIdx.x, lane = tid & 63, w = tid >> 6;
    int chunk = blockIdx.x*4 + w;
    int n = chunk*64 + lane;
    int a = assignv[n];
    ids[w][lane] = a;
    __syncthreads();
    int r = 0;
    #pragma unroll 8
    for (int m = 0; m < 64; ++m) {
        int am = ids[w][m];
        r += (m < lane && am == a) ? 1 : 0;
    }
    order[chunkoff[(size_t)chunk*K + a] + r] = n;
}

// ---------------- fold: exact np.add.at replication (ascending-n fp32 left-fold) ----------------
__global__ __launch_bounds__(128) void s_fold(const float* __restrict__ x0,
        const int* __restrict__ order, const int* __restrict__ startk,
        const int* __restrict__ cntk, float* __restrict__ sums)
{
    #pragma clang fp contract(off)
    const int k = blockIdx.x, d = threadIdx.x;
    const int start = startk[k], cnt = cntk[k];
    float s = 0.f;
    for (int i = 0; i < cnt; ++i) {
        int n = order[start + i];
        s = s + x0[(size_t)n*DIM + d];
    }
    sums[(size_t)k*DIM + d] = s;
}

// ---------------- centers update ----------------
__global__ void s_update(const float* __restrict__ sums, const float* __restrict__ cntf,
                         float* __restrict__ centers)
{
    int t = blockIdx.x*256 + threadIdx.x;
    int k = t >> 7;
    float c = cntf[k];
    float nv = sums[t] / fmaxf(c, 1.f);    // IEEE fp32 divide == np
    if (c > 0.f) centers[t] = nv;          // np.where(counts>0, new, old)
}

// ---------------- M = W @ centers / 128, plus centers -> output copy ----------------
__global__ void k_makeM(const float* __restrict__ W, const float* __restrict__ centers,
                        float* __restrict__ M, float* __restrict__ out_centers)
{
    int k = blockIdx.x, d = threadIdx.x;
    float s = 0.f;
    #pragma unroll 8
    for (int i = 0; i < K; ++i) s = fmaf(W[k*K + i], centers[i*DIM + d], s);
    M[k*DIM + d] = s * (1.f/128.f);
    out_centers[k*DIM + d] = centers[k*DIM + d];
}

// ---------------- out[n][k] = dot(x[n], M[k]) ----------------
__global__ __launch_bounds__(256, 1) void k_out(
    const float* __restrict__ x, const float* __restrict__ M, float* __restrict__ outp)
{
    __shared__ float mT[DIM][K+4];
    __shared__ float xT[4][DIM][8];
    const int tid = threadIdx.x, lane = tid & 63, w = tid >> 6;

    for (int idx = tid; idx < K*DIM; idx += 256) {
        int d = idx & (DIM-1);
        int kk = idx >> 7;
        mT[d][kk] = M[idx];
    }
    __syncthreads();

    const int block_base = blockIdx.x * 256;
    for (int pass = 0; pass < 8; ++pass) {
        const int base = block_base + pass*32 + w*8;
        #pragma unroll
        for (int j = 0; j < 4; ++j) {
            int f4 = lane + 64*j;
            int p = f4 & 7, dblk = f4 >> 3;
            float4 v = *(const float4*)&x[(size_t)(base+p)*DIM + 4*dblk];
            xT[w][4*dblk+0][p] = v.x;
            xT[w][4*dblk+1][p] = v.y;
            xT[w][4*dblk+2][p] = v.z;
            xT[w][4*dblk+3][p] = v.w;
        }
        __syncthreads();

        float acc[8][4];
        #pragma unroll
        for (int p = 0; p < 8; ++p)
            #pragma unroll
            for (int j = 0; j < 4; ++j) acc[p][j] = 0.f;

        #pragma unroll 2
        for (int d = 0; d < DIM; ++d) {
            const float4 c  = *(const float4*)&mT[d][4*lane];
            const float4 xa = *(const float4*)&xT[w][d][0];
            const float4 xb = *(const float4*)&xT[w][d][4];
            const float xs[8] = {xa.x,xa.y,xa.z,xa.w,xb.x,xb.y,xb.z,xb.w};
            const float cc[4] = {c.x,c.y,c.z,c.w};
            #pragma unroll
            for (int p = 0; p < 8; ++p)
                #pragma unroll
                for (int j = 0; j < 4; ++j)
                    acc[p][j] = fmaf(xs[p], cc[j], acc[p][j]);
        }

        #pragma unroll
        for (int p = 0; p < 8; ++p) {
            float4 o = make_float4(acc[p][0], acc[p][1], acc[p][2], acc[p][3]);
            *(float4*)&outp[(size_t)(base+p)*K + 4*lane] = o;
        }
        __syncthreads();
    }
}

extern "C" void kernel_launch(void* const* d_in, const int* in_sizes, int n_in,
                              void* d_out, int out_size, void* d_ws, size_t ws_size,
                              hipStream_t stream)
{
    const float* x = (const float*)d_in[0];   // [8][32768][128]
    const float* W = (const float*)d_in[1];   // [256][256]
    float* outp        = (float*)d_out;                       // [262144][256]
    float* out_centers = outp + (size_t)NALL * K;             // [256][128]

    // workspace layout (4B units)
    float* ws       = (float*)d_ws;
    float* centers  = ws;                          // 32768
    int*   assignv  = (int*)(ws + 32768);          // 32768
    float* Mbuf     = ws + 65536;                  // 32768
    float* sums     = ws + 98304;                  // 32768
    int*   counts   = (int*)(ws + 131072);         // 512*256 = 131072
    int*   chunkoff = (int*)(ws + 262144);         // 131072
    int*   order    = (int*)(ws + 393216);         // 32768
    int*   startk   = (int*)(ws + 425984);         // 256
    int*   cntk     = (int*)(ws + 426240);         // 256
    float* cntf     = ws + 426496;                 // 256
    (void)ws_size;

    k_init<<<128, 256, 0, stream>>>(x, centers);
    for (int it = 0; it < ITERS; ++it) {
        k_assign <<<NPTS/128, 256, 0, stream>>>(x, centers, assignv);
        s_count  <<<NCHUNK/4, 256, 0, stream>>>(assignv, counts);
        s_offset <<<1, 256, 0, stream>>>(counts, chunkoff, startk, cntk, cntf);
        s_scatter<<<NCHUNK/4, 256, 0, stream>>>(assignv, chunkoff, order);
        s_fold   <<<K, 128, 0, stream>>>(x, order, startk, cntk, sums);
        s_update <<<128, 256, 0, stream>>>(sums, cntf, centers);
    }
    k_makeM<<<K, DIM, 0, stream>>>(W, centers, Mbuf, out_centers);
    k_out<<<NALL/256, 256, 0, stream>>>(x, Mbuf, outp);
}

// Round 5
// 1681.639 us; speedup vs baseline: 1.8025x; 1.8025x over previous
//
#include <hip/hip_runtime.h>

#define DIM    128
#define K      256
#define NPTS   32768
#define NALL   (8*32768)
#define ITERS  10
#define NCHUNK 512            // 64 points per chunk for the stable sort

// numpy pairwise sum of squares, n=128, SSE2 path (the real x86-64 code path):
//   c[j] = sq[j] + sq[8+j] + ... + sq[120+j]  (ascending, j=0..7)
//   v_l  = c_l + c_{l+4}                       (_mm_add_ps(r0, r1))
//   res  = (v0 + v2) + (v1 + v3)               (movehl hsum + add_ss)
__device__ __forceinline__ float np_sumsq128(const float* p, int stride) {
    #pragma clang fp contract(off)
    float c[8];
    #pragma unroll
    for (int j = 0; j < 8; ++j) { float x = p[j*stride]; c[j] = x*x; }
    #pragma unroll
    for (int t = 1; t < 16; ++t)
        #pragma unroll
        for (int j = 0; j < 8; ++j) { float x = p[(8*t+j)*stride]; c[j] = c[j] + x*x; }
    float v0 = c[0] + c[4];
    float v1 = c[1] + c[5];
    float v2 = c[2] + c[6];
    float v3 = c[3] + c[7];
    return (v0 + v2) + (v1 + v3);
}

// ---------------- init: centers = X0[:256] ----------------
__global__ void k_init(const float* __restrict__ x0, float* __restrict__ centers) {
    int i = blockIdx.x * blockDim.x + threadIdx.x;
    if (i < K*DIM) centers[i] = x0[i];
}

// ---------------- assignment: bit-replication of np d2 + argmin ----------------
// d2 = fl(fl(x_sq + c_sq) - fl(2*dot)), dot = ascending-k fp32 FMA chain (BLAS).
// grid 256 blocks x 256 thr; block = 128 points (4 passes x 4 waves x 8 points)
__global__ __launch_bounds__(256, 1) void k_assign(
    const float* __restrict__ x0, const float* __restrict__ centers,
    int* __restrict__ assignv)
{
    __shared__ float cT[DIM][K+4];     // centers transposed, +4 pad
    __shared__ float xT[4][DIM][8];    // per-wave 8-point x tile
    __shared__ float csq[K];
    __shared__ float xsq[4][8];

    const int tid  = threadIdx.x;
    const int lane = tid & 63;
    const int w    = tid >> 6;

    for (int idx = tid; idx < K*DIM; idx += 256) {
        int d = idx & (DIM-1);
        int kk = idx >> 7;
        cT[d][kk] = centers[idx];       // idx == kk*128+d (coalesced)
    }
    __syncthreads();
    csq[tid] = np_sumsq128(&cT[0][tid], K+4);   // thread tid handles center k=tid
    __syncthreads();

    const float4 cs4 = *(const float4*)&csq[4*lane];

    const int block_base = blockIdx.x * 128;
    for (int pass = 0; pass < 4; ++pass) {
        const int base = block_base + pass*32 + w*8;
        #pragma unroll
        for (int j = 0; j < 4; ++j) {
            int f4 = lane + 64*j;
            int p = f4 & 7, dblk = f4 >> 3;
            float4 v = *(const float4*)&x0[(size_t)(base+p)*DIM + 4*dblk];
            xT[w][4*dblk+0][p] = v.x;
            xT[w][4*dblk+1][p] = v.y;
            xT[w][4*dblk+2][p] = v.z;
            xT[w][4*dblk+3][p] = v.w;
        }
        __syncthreads();

        if (lane < 8) xsq[w][lane] = np_sumsq128(&xT[w][0][lane], 8);
        __syncthreads();

        float acc[8][4];
        #pragma unroll
        for (int p = 0; p < 8; ++p)
            #pragma unroll
            for (int j = 0; j < 4; ++j) acc[p][j] = 0.f;

        // ascending-d fp32 FMA chains == BLAS sgemm per-element order
        for (int d = 0; d < DIM; ++d) {
            const float4 c  = *(const float4*)&cT[d][4*lane];
            const float4 xa = *(const float4*)&xT[w][d][0];
            const float4 xb = *(const float4*)&xT[w][d][4];
            const float xs[8] = {xa.x,xa.y,xa.z,xa.w,xb.x,xb.y,xb.z,xb.w};
            const float cc[4] = {c.x,c.y,c.z,c.w};
            #pragma unroll
            for (int p = 0; p < 8; ++p)
                #pragma unroll
                for (int j = 0; j < 4; ++j)
                    acc[p][j] = fmaf(xs[p], cc[j], acc[p][j]);
        }

        #pragma unroll
        for (int p = 0; p < 8; ++p) {
            #pragma clang fp contract(off)
            const float xs_ = xsq[w][p];
            float bv; int bi;
            { float m = 2.f*acc[p][0]; float t = xs_ + cs4.x; bv = t - m; bi = 4*lane; }
            { float m = 2.f*acc[p][1]; float t = xs_ + cs4.y; float v = t - m; if (v < bv) { bv=v; bi=4*lane+1; } }
            { float m = 2.f*acc[p][2]; float t = xs_ + cs4.z; float v = t - m; if (v < bv) { bv=v; bi=4*lane+2; } }
            { float m = 2.f*acc[p][3]; float t = xs_ + cs4.w; float v = t - m; if (v < bv) { bv=v; bi=4*lane+3; } }
            #pragma unroll
            for (int off = 32; off > 0; off >>= 1) {
                float ov = __shfl_xor(bv, off);
                int   oi = __shfl_xor(bi, off);
                if (ov < bv || (ov == bv && oi < bi)) { bv = ov; bi = oi; }
            }
            if (lane == p) assignv[base + p] = bi;   // first-min tie rule == np.argmin
        }
        __syncthreads();
    }
}

// ---------------- stable counting sort: counts per chunk ----------------
__global__ __launch_bounds__(256) void s_count(const int* __restrict__ assignv,
                                               int* __restrict__ counts)
{
    __shared__ int cnt[4][K];
    const int tid = threadIdx.x, lane = tid & 63, w = tid >> 6;
    for (int i = tid; i < 4*K; i += 256) ((int*)cnt)[i] = 0;
    __syncthreads();
    int chunk = blockIdx.x*4 + w;
    int a = assignv[chunk*64 + lane];
    atomicAdd(&cnt[w][a], 1);
    __syncthreads();
    for (int i = tid; i < 4*K; i += 256) {
        int w2 = i >> 8, k = i & 255;
        counts[(size_t)(blockIdx.x*4 + w2)*K + k] = cnt[w2][k];
    }
}

// ---------------- offsets: per-(chunk,k) absolute start positions ----------------
// batched independent loads -> latency-pipelined (was: 512-deep serial chain)
__global__ void s_offset(const int* __restrict__ counts, int* __restrict__ chunkoff,
                         int* __restrict__ startk, int* __restrict__ cntk,
                         float* __restrict__ cntf)
{
    __shared__ int tot[K], base[K];
    const int k = threadIdx.x;

    // pass 1: per-k total (batch-8 independent loads)
    int tk = 0;
    for (int ci = 0; ci < NCHUNK; ci += 8) {
        int c[8];
        #pragma unroll
        for (int j = 0; j < 8; ++j) c[j] = counts[(size_t)(ci+j)*K + k];
        #pragma unroll
        for (int j = 0; j < 8; ++j) tk += c[j];
    }
    tot[k] = tk;
    __syncthreads();
    if (k == 0) {
        int acc = 0;
        for (int i = 0; i < K; ++i) { base[i] = acc; acc += tot[i]; }
    }
    __syncthreads();

    // pass 2: running prefix (counts re-read, L2-hot) + base, write chunkoff once
    int running = base[k];
    for (int ci = 0; ci < NCHUNK; ci += 8) {
        int c[8];
        #pragma unroll
        for (int j = 0; j < 8; ++j) c[j] = counts[(size_t)(ci+j)*K + k];
        #pragma unroll
        for (int j = 0; j < 8; ++j) {
            chunkoff[(size_t)(ci+j)*K + k] = running;
            running += c[j];
        }
    }
    startk[k] = base[k];
    cntk[k]   = tot[k];
    cntf[k]   = (float)tot[k];
}

// ---------------- stable scatter: order[] = point indices grouped by cluster, ascending n ----------------
__global__ __launch_bounds__(256) void s_scatter(const int* __restrict__ assignv,
        const int* __restrict__ chunkoff, int* __restrict__ order)
{
    __shared__ int ids[4][64];
    const int tid = threadIdx.x, lane = tid & 63, w = tid >> 6;
    int chunk = blockIdx.x*4 + w;
    int n = chunk*64 + lane;
    int a = assignv[n];
    ids[w][lane] = a;
    __syncthreads();
    int r = 0;
    #pragma unroll 8
    for (int m = 0; m < 64; ++m) {
        int am = ids[w][m];
        r += (m < lane && am == a) ? 1 : 0;
    }
    order[chunkoff[(size_t)chunk*K + a] + r] = n;
}

// ---------------- fold: exact np.add.at replication (ascending-n fp32 left-fold) ----------------
// Adds stay in exact ascending-n order; loads are batched 16-wide for MLP.
__global__ __launch_bounds__(128) void s_fold(const float* __restrict__ x0,
        const int* __restrict__ order, const int* __restrict__ startk,
        const int* __restrict__ cntk, float* __restrict__ sums)
{
    #pragma clang fp contract(off)
    const int k = blockIdx.x, d = threadIdx.x;
    const int start = startk[k], cnt = cntk[k];
    float s = 0.f;
    for (int i = 0; i < cnt; i += 16) {
        int nn[16];
        #pragma unroll
        for (int j = 0; j < 16; ++j) {
            int idx = start + i + j;
            nn[j] = order[idx < NPTS ? idx : 0];          // safe over-read
        }
        float vv[16];
        #pragma unroll
        for (int j = 0; j < 16; ++j) vv[j] = x0[(size_t)nn[j]*DIM + d];
        #pragma unroll
        for (int j = 0; j < 16; ++j) {
            float t = s + vv[j];
            s = (i + j < cnt) ? t : s;                    // uniform select, exact order kept
        }
    }
    sums[(size_t)k*DIM + d] = s;
}

// ---------------- centers update ----------------
__global__ void s_update(const float* __restrict__ sums, const float* __restrict__ cntf,
                         float* __restrict__ centers)
{
    int t = blockIdx.x*256 + threadIdx.x;
    int k = t >> 7;
    float c = cntf[k];
    float nv = sums[t] / fmaxf(c, 1.f);    // IEEE fp32 divide == np
    if (c > 0.f) centers[t] = nv;          // np.where(counts>0, new, old)
}

// ---------------- M = W @ centers / 128, plus centers -> output copy ----------------
__global__ void k_makeM(const float* __restrict__ W, const float* __restrict__ centers,
                        float* __restrict__ M, float* __restrict__ out_centers)
{
    int k = blockIdx.x, d = threadIdx.x;
    float s = 0.f;
    #pragma unroll 8
    for (int i = 0; i < K; ++i) s = fmaf(W[k*K + i], centers[i*DIM + d], s);
    M[k*DIM + d] = s * (1.f/128.f);
    out_centers[k*DIM + d] = centers[k*DIM + d];
}

// ---------------- out[n][k] = dot(x[n], M[k]) ----------------
__global__ __launch_bounds__(256, 1) void k_out(
    const float* __restrict__ x, const float* __restrict__ M, float* __restrict__ outp)
{
    __shared__ float mT[DIM][K+4];
    __shared__ float xT[4][DIM][8];
    const int tid = threadIdx.x, lane = tid & 63, w = tid >> 6;

    for (int idx = tid; idx < K*DIM; idx += 256) {
        int d = idx & (DIM-1);
        int kk = idx >> 7;
        mT[d][kk] = M[idx];
    }
    __syncthreads();

    const int block_base = blockIdx.x * 256;
    for (int pass = 0; pass < 8; ++pass) {
        const int base = block_base + pass*32 + w*8;
        #pragma unroll
        for (int j = 0; j < 4; ++j) {
            int f4 = lane + 64*j;
            int p = f4 & 7, dblk = f4 >> 3;
            float4 v = *(const float4*)&x[(size_t)(base+p)*DIM + 4*dblk];
            xT[w][4*dblk+0][p] = v.x;
            xT[w][4*dblk+1][p] = v.y;
            xT[w][4*dblk+2][p] = v.z;
            xT[w][4*dblk+3][p] = v.w;
        }
        __syncthreads();

        float acc[8][4];
        #pragma unroll
        for (int p = 0; p < 8; ++p)
            #pragma unroll
            for (int j = 0; j < 4; ++j) acc[p][j] = 0.f;

        #pragma unroll 2
        for (int d = 0; d < DIM; ++d) {
            const float4 c  = *(const float4*)&mT[d][4*lane];
            const float4 xa = *(const float4*)&xT[w][d][0];
            const float4 xb = *(const float4*)&xT[w][d][4];
            const float xs[8] = {xa.x,xa.y,xa.z,xa.w,xb.x,xb.y,xb.z,xb.w};
            const float cc[4] = {c.x,c.y,c.z,c.w};
            #pragma unroll
            for (int p = 0; p < 8; ++p)
                #pragma unroll
                for (int j = 0; j < 4; ++j)
                    acc[p][j] = fmaf(xs[p], cc[j], acc[p][j]);
        }

        #pragma unroll
        for (int p = 0; p < 8; ++p) {
            float4 o = make_float4(acc[p][0], acc[p][1], acc[p][2], acc[p][3]);
            *(float4*)&outp[(size_t)(base+p)*K + 4*lane] = o;
        }
        __syncthreads();
    }
}

extern "C" void kernel_launch(void* const* d_in, const int* in_sizes, int n_in,
                              void* d_out, int out_size, void* d_ws, size_t ws_size,
                              hipStream_t stream)
{
    const float* x = (const float*)d_in[0];   // [8][32768][128]
    const float* W = (const float*)d_in[1];   // [256][256]
    float* outp        = (float*)d_out;                       // [262144][256]
    float* out_centers = outp + (size_t)NALL * K;             // [256][128]

    // workspace layout (4B units)
    float* ws       = (float*)d_ws;
    float* centers  = ws;                          // 32768
    int*   assignv  = (int*)(ws + 32768);          // 32768
    float* Mbuf     = ws + 65536;                  // 32768
    float* sums     = ws + 98304;                  // 32768
    int*   counts   = (int*)(ws + 131072);         // 512*256 = 131072
    int*   chunkoff = (int*)(ws + 262144);         // 131072
    int*   order    = (int*)(ws + 393216);         // 32768
    int*   startk   = (int*)(ws + 425984);         // 256
    int*   cntk     = (int*)(ws + 426240);         // 256
    float* cntf     = ws + 426496;                 // 256
    (void)ws_size;

    k_init<<<128, 256, 0, stream>>>(x, centers);
    for (int it = 0; it < ITERS; ++it) {
        k_assign <<<NPTS/128, 256, 0, stream>>>(x, centers, assignv);
        s_count  <<<NCHUNK/4, 256, 0, stream>>>(assignv, counts);
        s_offset <<<1, 256, 0, stream>>>(counts, chunkoff, startk, cntk, cntf);
        s_scatter<<<NCHUNK/4, 256, 0, stream>>>(assignv, chunkoff, order);
        s_fold   <<<K, 128, 0, stream>>>(x, order, startk, cntk, sums);
        s_update <<<128, 256, 0, stream>>>(sums, cntf, centers);
    }
    k_makeM<<<K, DIM, 0, stream>>>(W, centers, Mbuf, out_centers);
    k_out<<<NALL/256, 256, 0, stream>>>(x, Mbuf, outp);
}

// Round 6
// 1614.580 us; speedup vs baseline: 1.8774x; 1.0415x over previous
//
#include <hip/hip_runtime.h>

#define DIM    128
#define K      256
#define NPTS   32768
#define NALL   (8*32768)
#define ITERS  10
#define NCHUNK 512            // 64 points per chunk for the stable sort

typedef short bf16x8 __attribute__((ext_vector_type(8)));
typedef float f32x4  __attribute__((ext_vector_type(4)));

// fp32 -> bf16 RNE (bit trick), returns ushort
__device__ __forceinline__ unsigned short bf16_rne(float f) {
    unsigned int u = __float_as_uint(f);
    unsigned int r = u + 0x7fffu + ((u >> 16) & 1u);
    return (unsigned short)(r >> 16);
}
__device__ __forceinline__ float bf16_to_f(unsigned short h) {
    return __uint_as_float(((unsigned int)h) << 16);
}

// numpy pairwise sum of squares, n=128, SSE2 path (the real x86-64 code path):
//   c[j] = sq[j] + sq[8+j] + ... + sq[120+j]  (ascending, j=0..7)
//   v_l  = c_l + c_{l+4};  res = (v0 + v2) + (v1 + v3)
__device__ __forceinline__ float np_sumsq128(const float* p, int stride) {
    #pragma clang fp contract(off)
    float c[8];
    #pragma unroll
    for (int j = 0; j < 8; ++j) { float x = p[j*stride]; c[j] = x*x; }
    #pragma unroll
    for (int t = 1; t < 16; ++t)
        #pragma unroll
        for (int j = 0; j < 8; ++j) { float x = p[(8*t+j)*stride]; c[j] = c[j] + x*x; }
    float v0 = c[0] + c[4];
    float v1 = c[1] + c[5];
    float v2 = c[2] + c[6];
    float v3 = c[3] + c[7];
    return (v0 + v2) + (v1 + v3);
}

// ---------------- init: centers = X0[:256] ----------------
__global__ void k_init(const float* __restrict__ x0, float* __restrict__ centers) {
    int i = blockIdx.x * blockDim.x + threadIdx.x;
    if (i < K*DIM) centers[i] = x0[i];
}

// ---------------- assignment (+fused per-chunk counts) ----------------
// d2 = fl(fl(x_sq + c_sq) - fl(2*dot)), dot = ascending-k fp32 FMA chain (BLAS).
// grid 256 blocks x 256 thr; block = 128 points (4 passes x 4 waves x 8 points)
__global__ __launch_bounds__(256, 1) void k_assign(
    const float* __restrict__ x0, const float* __restrict__ centers,
    int* __restrict__ assignv, int* __restrict__ counts)
{
    __shared__ float cT[DIM][K+4];     // centers transposed, +4 pad
    __shared__ float xT[4][DIM][8];    // per-wave 8-point x tile
    __shared__ float csq[K];
    __shared__ float xsq[4][8];
    __shared__ int   cnt2[2][K];       // fused s_count (2 chunks of 64 pts)

    const int tid  = threadIdx.x;
    const int lane = tid & 63;
    const int w    = tid >> 6;

    for (int i = tid; i < 2*K; i += 256) ((int*)cnt2)[i] = 0;
    for (int idx = tid; idx < K*DIM; idx += 256) {
        int d = idx & (DIM-1);
        int kk = idx >> 7;
        cT[d][kk] = centers[idx];       // idx == kk*128+d (coalesced)
    }
    __syncthreads();
    csq[tid] = np_sumsq128(&cT[0][tid], K+4);
    __syncthreads();

    const float4 cs4 = *(const float4*)&csq[4*lane];

    const int block_base = blockIdx.x * 128;
    for (int pass = 0; pass < 4; ++pass) {
        const int base = block_base + pass*32 + w*8;
        #pragma unroll
        for (int j = 0; j < 4; ++j) {
            int f4 = lane + 64*j;
            int p = f4 & 7, dblk = f4 >> 3;
            float4 v = *(const float4*)&x0[(size_t)(base+p)*DIM + 4*dblk];
            xT[w][4*dblk+0][p] = v.x;
            xT[w][4*dblk+1][p] = v.y;
            xT[w][4*dblk+2][p] = v.z;
            xT[w][4*dblk+3][p] = v.w;
        }
        __syncthreads();

        if (lane < 8) xsq[w][lane] = np_sumsq128(&xT[w][0][lane], 8);
        __syncthreads();

        float acc[8][4];
        #pragma unroll
        for (int p = 0; p < 8; ++p)
            #pragma unroll
            for (int j = 0; j < 4; ++j) acc[p][j] = 0.f;

        // ascending-d fp32 FMA chains == BLAS sgemm per-element order
        for (int d = 0; d < DIM; ++d) {
            const float4 c  = *(const float4*)&cT[d][4*lane];
            const float4 xa = *(const float4*)&xT[w][d][0];
            const float4 xb = *(const float4*)&xT[w][d][4];
            const float xs[8] = {xa.x,xa.y,xa.z,xa.w,xb.x,xb.y,xb.z,xb.w};
            const float cc[4] = {c.x,c.y,c.z,c.w};
            #pragma unroll
            for (int p = 0; p < 8; ++p)
                #pragma unroll
                for (int j = 0; j < 4; ++j)
                    acc[p][j] = fmaf(xs[p], cc[j], acc[p][j]);
        }

        #pragma unroll
        for (int p = 0; p < 8; ++p) {
            #pragma clang fp contract(off)
            const float xs_ = xsq[w][p];
            float bv; int bi;
            { float m = 2.f*acc[p][0]; float t = xs_ + cs4.x; bv = t - m; bi = 4*lane; }
            { float m = 2.f*acc[p][1]; float t = xs_ + cs4.y; float v = t - m; if (v < bv) { bv=v; bi=4*lane+1; } }
            { float m = 2.f*acc[p][2]; float t = xs_ + cs4.z; float v = t - m; if (v < bv) { bv=v; bi=4*lane+2; } }
            { float m = 2.f*acc[p][3]; float t = xs_ + cs4.w; float v = t - m; if (v < bv) { bv=v; bi=4*lane+3; } }
            #pragma unroll
            for (int off = 32; off > 0; off >>= 1) {
                float ov = __shfl_xor(bv, off);
                int   oi = __shfl_xor(bi, off);
                if (ov < bv || (ov == bv && oi < bi)) { bv = ov; bi = oi; }
            }
            if (lane == p) {
                assignv[base + p] = bi;                         // first-min tie rule == np.argmin
                int pt = pass*32 + w*8 + p;                     // 0..127 within block
                atomicAdd(&cnt2[pt >> 6][bi], 1);
            }
        }
        __syncthreads();
    }

    for (int i = tid; i < 2*K; i += 256) {
        int h = i >> 8, kk = i & 255;
        counts[(size_t)(blockIdx.x*2 + h)*K + kk] = cnt2[h][kk];
    }
}

// ---------------- offsets: parallel (4 threads per k) ----------------
__global__ __launch_bounds__(1024) void s_offset(
    const int* __restrict__ counts, int* __restrict__ chunkoff,
    int* __restrict__ startk, int* __restrict__ cntk, float* __restrict__ cntf)
{
    __shared__ int part[K][4];
    __shared__ int basearr[K];
    __shared__ int wsum[4];
    const int t = threadIdx.x;          // 0..1023
    const int k = t >> 2, q = t & 3;

    int s = 0;
    for (int j0 = 0; j0 < 128; j0 += 16) {
        int c[16];
        #pragma unroll
        for (int j = 0; j < 16; ++j) c[j] = counts[(size_t)(q*128 + j0 + j)*K + k];
        #pragma unroll
        for (int j = 0; j < 16; ++j) s += c[j];
    }
    part[k][q] = s;
    __syncthreads();

    int my_tot = 0, incl = 0;
    if (t < K) {
        my_tot = part[t][0] + part[t][1] + part[t][2] + part[t][3];
        incl = my_tot;
        #pragma unroll
        for (int off = 1; off < 64; off <<= 1) {
            int o = __shfl_up(incl, off);
            if ((t & 63) >= off) incl += o;
        }
        if ((t & 63) == 63) wsum[t >> 6] = incl;
    }
    __syncthreads();
    if (t < K) {
        int wo = 0;
        for (int ww = 0; ww < (t >> 6); ++ww) wo += wsum[ww];
        int base = incl + wo - my_tot;   // exclusive prefix
        basearr[t] = base;
        startk[t]  = base;
        cntk[t]    = my_tot;
        cntf[t]    = (float)my_tot;
    }
    __syncthreads();

    int running = basearr[k];
    #pragma unroll
    for (int qq = 0; qq < 3; ++qq) if (qq < q) running += part[k][qq];
    for (int j0 = 0; j0 < 128; j0 += 16) {
        int c[16];
        #pragma unroll
        for (int j = 0; j < 16; ++j) c[j] = counts[(size_t)(q*128 + j0 + j)*K + k];
        #pragma unroll
        for (int j = 0; j < 16; ++j) {
            chunkoff[(size_t)(q*128 + j0 + j)*K + k] = running;
            running += c[j];
        }
    }
}

// ---------------- stable scatter ----------------
__global__ __launch_bounds__(256) void s_scatter(const int* __restrict__ assignv,
        const int* __restrict__ chunkoff, int* __restrict__ order)
{
    __shared__ int ids[4][64];
    const int tid = threadIdx.x, lane = tid & 63, w = tid >> 6;
    int chunk = blockIdx.x*4 + w;
    int n = chunk*64 + lane;
    int a = assignv[n];
    ids[w][lane] = a;
    __syncthreads();
    int r = 0;
    #pragma unroll 8
    for (int m = 0; m < 64; ++m) {
        int am = ids[w][m];
        r += (m < lane && am == a) ? 1 : 0;
    }
    order[chunkoff[(size_t)chunk*K + a] + r] = n;
}

// ---------------- fold: exact np.add.at replication ----------------
__global__ __launch_bounds__(128) void s_fold(const float* __restrict__ x0,
        const int* __restrict__ order, const int* __restrict__ startk,
        const int* __restrict__ cntk, float* __restrict__ sums)
{
    #pragma clang fp contract(off)
    const int k = blockIdx.x, d = threadIdx.x;
    const int start = startk[k], cnt = cntk[k];
    float s = 0.f;
    for (int i = 0; i < cnt; i += 16) {
        int nn[16];
        #pragma unroll
        for (int j = 0; j < 16; ++j) {
            int idx = start + i + j;
            nn[j] = order[idx < NPTS ? idx : 0];
        }
        float vv[16];
        #pragma unroll
        for (int j = 0; j < 16; ++j) vv[j] = x0[(size_t)nn[j]*DIM + d];
        #pragma unroll
        for (int j = 0; j < 16; ++j) {
            float t = s + vv[j];
            s = (i + j < cnt) ? t : s;
        }
    }
    sums[(size_t)k*DIM + d] = s;
}

// ---------------- centers update ----------------
__global__ void s_update(const float* __restrict__ sums, const float* __restrict__ cntf,
                         float* __restrict__ centers)
{
    int t = blockIdx.x*256 + threadIdx.x;
    int k = t >> 7;
    float c = cntf[k];
    float nv = sums[t] / fmaxf(c, 1.f);
    if (c > 0.f) centers[t] = nv;
}

// ---------------- M = W @ centers / 128 (fp32), split to bf16 hi/lo ----------------
__global__ void k_makeM(const float* __restrict__ W, const float* __restrict__ centers,
                        unsigned short* __restrict__ Mh, unsigned short* __restrict__ Ml,
                        float* __restrict__ out_centers)
{
    int k = blockIdx.x, d = threadIdx.x;
    float s = 0.f;
    #pragma unroll 8
    for (int i = 0; i < K; ++i) s = fmaf(W[k*K + i], centers[i*DIM + d], s);
    s *= (1.f/128.f);
    unsigned short h = bf16_rne(s);
    float lo = s - bf16_to_f(h);
    unsigned short l2 = bf16_rne(lo);
    Mh[k*DIM + d] = h;
    Ml[k*DIM + d] = l2;
    out_centers[k*DIM + d] = centers[k*DIM + d];
}

// ---------------- out = X @ M^T via bf16-split MFMA ----------------
// block = 256 thr (4 waves); wave w owns cols [64w, 64w+64) (4 col-tiles).
// strip = 32 rows; grid-stride over 8192 strips. B (Mh/Ml frags) in registers.
__global__ __launch_bounds__(256, 2) void k_out_mfma(
    const float* __restrict__ x, const unsigned short* __restrict__ Mh,
    const unsigned short* __restrict__ Ml, float* __restrict__ outp)
{
    __shared__ unsigned short AhL[32][DIM+8];
    __shared__ unsigned short AlL[32][DIM+8];

    const int tid = threadIdx.x, lane = tid & 63, w = tid >> 6;

    // B fragments: bh/bl[tt][s], tile tt -> cols 64w+16tt.., kstep s -> k 32s..
    bf16x8 bh[4][4], bl[4][4];
    #pragma unroll
    for (int tt = 0; tt < 4; ++tt)
        #pragma unroll
        for (int s = 0; s < 4; ++s) {
            int col = (w*4 + tt)*16 + (lane & 15);
            int off = col*DIM + 32*s + (lane >> 4)*8;
            bh[tt][s] = *(const bf16x8*)&Mh[off];
            bl[tt][s] = *(const bf16x8*)&Ml[off];
        }

    for (int strip = blockIdx.x; strip < NALL/32; strip += gridDim.x) {
        const int sbase = strip * 32;
        __syncthreads();   // prev strip's LDS reads done
        // stage + convert A: 32 rows x 128 cols fp32 -> bf16 hi/lo
        const float4* x4 = (const float4*)x;
        #pragma unroll
        for (int i = 0; i < 4; ++i) {
            int idx = i*256 + tid;          // 0..1023 float4s
            int row = idx >> 5, c4 = idx & 31;
            float4 v = x4[(size_t)(sbase + row)*32 + c4];
            ushort4 hh, ll;
            float f; unsigned short h;
            f = v.x; h = bf16_rne(f); hh.x = h; ll.x = bf16_rne(f - bf16_to_f(h));
            f = v.y; h = bf16_rne(f); hh.y = h; ll.y = bf16_rne(f - bf16_to_f(h));
            f = v.z; h = bf16_rne(f); hh.z = h; ll.z = bf16_rne(f - bf16_to_f(h));
            f = v.w; h = bf16_rne(f); hh.w = h; ll.w = bf16_rne(f - bf16_to_f(h));
            *(ushort4*)&AhL[row][c4*4] = hh;
            *(ushort4*)&AlL[row][c4*4] = ll;
        }
        __syncthreads();

        f32x4 acc[2][4];
        #pragma unroll
        for (int rt = 0; rt < 2; ++rt)
            #pragma unroll
            for (int tt = 0; tt < 4; ++tt)
                acc[rt][tt] = (f32x4){0.f, 0.f, 0.f, 0.f};

        #pragma unroll
        for (int s = 0; s < 4; ++s) {
            bf16x8 ah[2], al[2];
            #pragma unroll
            for (int rt = 0; rt < 2; ++rt) {
                int r = (lane & 15) + 16*rt;
                int kc = 32*s + (lane >> 4)*8;
                ah[rt] = *(const bf16x8*)&AhL[r][kc];
                al[rt] = *(const bf16x8*)&AlL[r][kc];
            }
            #pragma unroll
            for (int rt = 0; rt < 2; ++rt)
                #pragma unroll
                for (int tt = 0; tt < 4; ++tt) {
                    acc[rt][tt] = __builtin_amdgcn_mfma_f32_16x16x32_bf16(ah[rt], bh[tt][s], acc[rt][tt], 0, 0, 0);
                    acc[rt][tt] = __builtin_amdgcn_mfma_f32_16x16x32_bf16(ah[rt], bl[tt][s], acc[rt][tt], 0, 0, 0);
                    acc[rt][tt] = __builtin_amdgcn_mfma_f32_16x16x32_bf16(al[rt], bh[tt][s], acc[rt][tt], 0, 0, 0);
                }
        }

        // store: D row = (lane>>4)*4 + reg, col = lane&15 (within tile)
        #pragma unroll
        for (int rt = 0; rt < 2; ++rt)
            #pragma unroll
            for (int tt = 0; tt < 4; ++tt)
                #pragma unroll
                for (int reg = 0; reg < 4; ++reg) {
                    int row = sbase + rt*16 + (lane >> 4)*4 + reg;
                    int col = w*64 + tt*16 + (lane & 15);
                    outp[(size_t)row*K + col] = acc[rt][tt][reg];
                }
    }
}

extern "C" void kernel_launch(void* const* d_in, const int* in_sizes, int n_in,
                              void* d_out, int out_size, void* d_ws, size_t ws_size,
                              hipStream_t stream)
{
    const float* x = (const float*)d_in[0];   // [8][32768][128]
    const float* W = (const float*)d_in[1];   // [256][256]
    float* outp        = (float*)d_out;                       // [262144][256]
    float* out_centers = outp + (size_t)NALL * K;             // [256][128]

    // workspace layout (4B units)
    float* ws       = (float*)d_ws;
    float* centers  = ws;                              // 32768
    int*   assignv  = (int*)(ws + 32768);              // 32768
    float* sums     = ws + 65536;                      // 32768
    int*   counts   = (int*)(ws + 98304);              // 131072
    int*   chunkoff = (int*)(ws + 229376);             // 131072
    int*   order    = (int*)(ws + 360448);             // 32768
    int*   startk   = (int*)(ws + 393216);             // 256
    int*   cntk     = (int*)(ws + 393472);             // 256
    float* cntf     = ws + 393728;                     // 256
    unsigned short* Mh = (unsigned short*)(ws + 393984);  // 32768 ushort
    unsigned short* Ml = (unsigned short*)(ws + 410368);  // 32768 ushort
    (void)ws_size;

    k_init<<<128, 256, 0, stream>>>(x, centers);
    for (int it = 0; it < ITERS; ++it) {
        k_assign <<<NPTS/128, 256, 0, stream>>>(x, centers, assignv, counts);
        s_offset <<<1, 1024, 0, stream>>>(counts, chunkoff, startk, cntk, cntf);
        s_scatter<<<NCHUNK/4, 256, 0, stream>>>(assignv, chunkoff, order);
        s_fold   <<<K, 128, 0, stream>>>(x, order, startk, cntk, sums);
        s_update <<<128, 256, 0, stream>>>(sums, cntf, centers);
    }
    k_makeM<<<K, DIM, 0, stream>>>(W, centers, Mh, Ml, out_centers);
    k_out_mfma<<<2048, 256, 0, stream>>>(x, Mh, Ml, outp);
}

// Round 7
// 1550.643 us; speedup vs baseline: 1.9548x; 1.0412x over previous
//
#include <hip/hip_runtime.h>

#define DIM    128
#define K      256
#define NPTS   32768
#define NALL   (8*32768)
#define ITERS  10
#define NCHUNK 512            // 64 points per chunk for the stable sort
#define FT     64             // s_fold pipeline tile

typedef short bf16x8 __attribute__((ext_vector_type(8)));
typedef float f32x4  __attribute__((ext_vector_type(4)));

// fp32 -> bf16 RNE (bit trick), returns ushort
__device__ __forceinline__ unsigned short bf16_rne(float f) {
    unsigned int u = __float_as_uint(f);
    unsigned int r = u + 0x7fffu + ((u >> 16) & 1u);
    return (unsigned short)(r >> 16);
}
__device__ __forceinline__ float bf16_to_f(unsigned short h) {
    return __uint_as_float(((unsigned int)h) << 16);
}

// numpy pairwise sum of squares, n=128, SSE2 path (the real x86-64 code path):
//   c[j] = sq[j] + sq[8+j] + ... + sq[120+j]  (ascending, j=0..7)
//   v_l  = c_l + c_{l+4};  res = (v0 + v2) + (v1 + v3)
__device__ __forceinline__ float np_sumsq128(const float* p, int stride) {
    #pragma clang fp contract(off)
    float c[8];
    #pragma unroll
    for (int j = 0; j < 8; ++j) { float x = p[j*stride]; c[j] = x*x; }
    #pragma unroll
    for (int t = 1; t < 16; ++t)
        #pragma unroll
        for (int j = 0; j < 8; ++j) { float x = p[(8*t+j)*stride]; c[j] = c[j] + x*x; }
    float v0 = c[0] + c[4];
    float v1 = c[1] + c[5];
    float v2 = c[2] + c[6];
    float v3 = c[3] + c[7];
    return (v0 + v2) + (v1 + v3);
}

// ---------------- init: centers = X0[:256] ----------------
__global__ void k_init(const float* __restrict__ x0, float* __restrict__ centers) {
    int i = blockIdx.x * blockDim.x + threadIdx.x;
    if (i < K*DIM) centers[i] = x0[i];
}

// ---------------- assignment (+fused per-chunk counts) ----------------
// d2 = fl(fl(x_sq + c_sq) - fl(2*dot)), dot = ascending-k fp32 FMA chain (BLAS).
// grid 256 blocks x 256 thr; block = 128 points (4 passes x 4 waves x 8 points)
__global__ __launch_bounds__(256, 1) void k_assign(
    const float* __restrict__ x0, const float* __restrict__ centers,
    int* __restrict__ assignv, int* __restrict__ counts)
{
    __shared__ float cT[DIM][K+4];     // centers transposed, +4 pad
    __shared__ float xT[4][DIM][8];    // per-wave 8-point x tile
    __shared__ float csq[K];
    __shared__ float xsq[4][8];
    __shared__ int   cnt2[2][K];       // fused s_count (2 chunks of 64 pts)

    const int tid  = threadIdx.x;
    const int lane = tid & 63;
    const int w    = tid >> 6;

    for (int i = tid; i < 2*K; i += 256) ((int*)cnt2)[i] = 0;
    for (int idx = tid; idx < K*DIM; idx += 256) {
        int d = idx & (DIM-1);
        int kk = idx >> 7;
        cT[d][kk] = centers[idx];       // idx == kk*128+d (coalesced)
    }
    __syncthreads();
    csq[tid] = np_sumsq128(&cT[0][tid], K+4);
    __syncthreads();

    const float4 cs4 = *(const float4*)&csq[4*lane];

    const int block_base = blockIdx.x * 128;
    for (int pass = 0; pass < 4; ++pass) {
        const int base = block_base + pass*32 + w*8;
        #pragma unroll
        for (int j = 0; j < 4; ++j) {
            int f4 = lane + 64*j;
            int p = f4 & 7, dblk = f4 >> 3;
            float4 v = *(const float4*)&x0[(size_t)(base+p)*DIM + 4*dblk];
            xT[w][4*dblk+0][p] = v.x;
            xT[w][4*dblk+1][p] = v.y;
            xT[w][4*dblk+2][p] = v.z;
            xT[w][4*dblk+3][p] = v.w;
        }
        __syncthreads();

        if (lane < 8) xsq[w][lane] = np_sumsq128(&xT[w][0][lane], 8);
        __syncthreads();

        float acc[8][4];
        #pragma unroll
        for (int p = 0; p < 8; ++p)
            #pragma unroll
            for (int j = 0; j < 4; ++j) acc[p][j] = 0.f;

        // ascending-d fp32 FMA chains == BLAS sgemm per-element order
        for (int d = 0; d < DIM; ++d) {
            const float4 c  = *(const float4*)&cT[d][4*lane];
            const float4 xa = *(const float4*)&xT[w][d][0];
            const float4 xb = *(const float4*)&xT[w][d][4];
            const float xs[8] = {xa.x,xa.y,xa.z,xa.w,xb.x,xb.y,xb.z,xb.w};
            const float cc[4] = {c.x,c.y,c.z,c.w};
            #pragma unroll
            for (int p = 0; p < 8; ++p)
                #pragma unroll
                for (int j = 0; j < 4; ++j)
                    acc[p][j] = fmaf(xs[p], cc[j], acc[p][j]);
        }

        #pragma unroll
        for (int p = 0; p < 8; ++p) {
            #pragma clang fp contract(off)
            const float xs_ = xsq[w][p];
            float bv; int bi;
            { float m = 2.f*acc[p][0]; float t = xs_ + cs4.x; bv = t - m; bi = 4*lane; }
            { float m = 2.f*acc[p][1]; float t = xs_ + cs4.y; float v = t - m; if (v < bv) { bv=v; bi=4*lane+1; } }
            { float m = 2.f*acc[p][2]; float t = xs_ + cs4.z; float v = t - m; if (v < bv) { bv=v; bi=4*lane+2; } }
            { float m = 2.f*acc[p][3]; float t = xs_ + cs4.w; float v = t - m; if (v < bv) { bv=v; bi=4*lane+3; } }
            #pragma unroll
            for (int off = 32; off > 0; off >>= 1) {
                float ov = __shfl_xor(bv, off);
                int   oi = __shfl_xor(bi, off);
                if (ov < bv || (ov == bv && oi < bi)) { bv = ov; bi = oi; }
            }
            if (lane == p) {
                assignv[base + p] = bi;                         // first-min tie rule == np.argmin
                int pt = pass*32 + w*8 + p;                     // 0..127 within block
                atomicAdd(&cnt2[pt >> 6][bi], 1);
            }
        }
        __syncthreads();
    }

    for (int i = tid; i < 2*K; i += 256) {
        int h = i >> 8, kk = i & 255;
        counts[(size_t)(blockIdx.x*2 + h)*K + kk] = cnt2[h][kk];
    }
}

// ---------------- offsets: parallel (4 threads per k) ----------------
__global__ __launch_bounds__(1024) void s_offset(
    const int* __restrict__ counts, int* __restrict__ chunkoff,
    int* __restrict__ startk, int* __restrict__ cntk, float* __restrict__ cntf)
{
    __shared__ int part[K][4];
    __shared__ int basearr[K];
    __shared__ int wsum[4];
    const int t = threadIdx.x;          // 0..1023
    const int k = t >> 2, q = t & 3;

    int s = 0;
    for (int j0 = 0; j0 < 128; j0 += 16) {
        int c[16];
        #pragma unroll
        for (int j = 0; j < 16; ++j) c[j] = counts[(size_t)(q*128 + j0 + j)*K + k];
        #pragma unroll
        for (int j = 0; j < 16; ++j) s += c[j];
    }
    part[k][q] = s;
    __syncthreads();

    int my_tot = 0, incl = 0;
    if (t < K) {
        my_tot = part[t][0] + part[t][1] + part[t][2] + part[t][3];
        incl = my_tot;
        #pragma unroll
        for (int off = 1; off < 64; off <<= 1) {
            int o = __shfl_up(incl, off);
            if ((t & 63) >= off) incl += o;
        }
        if ((t & 63) == 63) wsum[t >> 6] = incl;
    }
    __syncthreads();
    if (t < K) {
        int wo = 0;
        for (int ww = 0; ww < (t >> 6); ++ww) wo += wsum[ww];
        int base = incl + wo - my_tot;   // exclusive prefix
        basearr[t] = base;
        startk[t]  = base;
        cntk[t]    = my_tot;
        cntf[t]    = (float)my_tot;
    }
    __syncthreads();

    int running = basearr[k];
    #pragma unroll
    for (int qq = 0; qq < 3; ++qq) if (qq < q) running += part[k][qq];
    for (int j0 = 0; j0 < 128; j0 += 16) {
        int c[16];
        #pragma unroll
        for (int j = 0; j < 16; ++j) c[j] = counts[(size_t)(q*128 + j0 + j)*K + k];
        #pragma unroll
        for (int j = 0; j < 16; ++j) {
            chunkoff[(size_t)(q*128 + j0 + j)*K + k] = running;
            running += c[j];
        }
    }
}

// ---------------- stable scatter ----------------
__global__ __launch_bounds__(256) void s_scatter(const int* __restrict__ assignv,
        const int* __restrict__ chunkoff, int* __restrict__ order)
{
    __shared__ int ids[4][64];
    const int tid = threadIdx.x, lane = tid & 63, w = tid >> 6;
    int chunk = blockIdx.x*4 + w;
    int n = chunk*64 + lane;
    int a = assignv[n];
    ids[w][lane] = a;
    __syncthreads();
    int r = 0;
    #pragma unroll 8
    for (int m = 0; m < 64; ++m) {
        int am = ids[w][m];
        r += (m < lane && am == a) ? 1 : 0;
    }
    order[chunkoff[(size_t)chunk*K + a] + r] = n;
}

// ---------------- fold: exact np.add.at replication, software-pipelined ----------------
// Exact ascending-n fp32 left-fold preserved; tiles of FT=64 double-buffered in
// registers so tile t+1's 64 independent gathers are in flight while tile t folds.
#define LOADT(vv, t0) do {                                                  \
    int base_ = start + (t0)*FT;                                            \
    int nn_[FT];                                                            \
    _Pragma("unroll")                                                       \
    for (int j = 0; j < FT; ++j) {                                          \
        int idx_ = base_ + j;                                               \
        nn_[j] = order[idx_ < NPTS ? idx_ : 0];                             \
    }                                                                       \
    _Pragma("unroll")                                                       \
    for (int j = 0; j < FT; ++j) vv[j] = x0[(size_t)nn_[j]*DIM + d];        \
} while (0)

#define FOLDT(vv, t0) do {                                                  \
    int rem_ = cnt - (t0)*FT;                                               \
    if (rem_ >= FT) {                                                       \
        _Pragma("unroll")                                                   \
        for (int j = 0; j < FT; ++j) s = s + vv[j];                         \
    } else if (rem_ > 0) {                                                  \
        _Pragma("unroll")                                                   \
        for (int j = 0; j < FT; ++j) { float t_ = s + vv[j]; s = (j < rem_) ? t_ : s; } \
    }                                                                       \
} while (0)

__global__ __launch_bounds__(128) void s_fold(const float* __restrict__ x0,
        const int* __restrict__ order, const int* __restrict__ startk,
        const int* __restrict__ cntk, float* __restrict__ sums)
{
    #pragma clang fp contract(off)
    const int k = blockIdx.x, d = threadIdx.x;
    const int start = startk[k], cnt = cntk[k];
    float vA[FT], vB[FT];
    float s = 0.f;
    const int nt = (cnt + FT - 1) / FT;

    if (nt > 0) {
        LOADT(vA, 0);
        for (int t = 0; t < nt; t += 2) {
            LOADT(vB, t+1);              // in flight while A folds
            FOLDT(vA, t);
            LOADT(vA, t+2);              // in flight while B folds
            FOLDT(vB, t+1);
        }
    }
    sums[(size_t)k*DIM + d] = s;
}

// ---------------- centers update ----------------
__global__ void s_update(const float* __restrict__ sums, const float* __restrict__ cntf,
                         float* __restrict__ centers)
{
    int t = blockIdx.x*256 + threadIdx.x;
    int k = t >> 7;
    float c = cntf[k];
    float nv = sums[t] / fmaxf(c, 1.f);
    if (c > 0.f) centers[t] = nv;
}

// ---------------- M = W @ centers / 128 (fp32), split to bf16 hi/lo ----------------
__global__ void k_makeM(const float* __restrict__ W, const float* __restrict__ centers,
                        unsigned short* __restrict__ Mh, unsigned short* __restrict__ Ml,
                        float* __restrict__ out_centers)
{
    int k = blockIdx.x, d = threadIdx.x;
    float s = 0.f;
    #pragma unroll 8
    for (int i = 0; i < K; ++i) s = fmaf(W[k*K + i], centers[i*DIM + d], s);
    s *= (1.f/128.f);
    unsigned short h = bf16_rne(s);
    float lo = s - bf16_to_f(h);
    unsigned short l2 = bf16_rne(lo);
    Mh[k*DIM + d] = h;
    Ml[k*DIM + d] = l2;
    out_centers[k*DIM + d] = centers[k*DIM + d];
}

// ---------------- out = X @ M^T via bf16-split MFMA ----------------
// block = 256 thr (4 waves); wave w owns cols [64w, 64w+64) (4 col-tiles).
// strip = 32 rows; grid-stride over 8192 strips. B (Mh/Ml frags) in registers.
__global__ __launch_bounds__(256, 2) void k_out_mfma(
    const float* __restrict__ x, const unsigned short* __restrict__ Mh,
    const unsigned short* __restrict__ Ml, float* __restrict__ outp)
{
    __shared__ unsigned short AhL[32][DIM+8];
    __shared__ unsigned short AlL[32][DIM+8];

    const int tid = threadIdx.x, lane = tid & 63, w = tid >> 6;

    // B fragments: bh/bl[tt][s], tile tt -> cols 64w+16tt.., kstep s -> k 32s..
    bf16x8 bh[4][4], bl[4][4];
    #pragma unroll
    for (int tt = 0; tt < 4; ++tt)
        #pragma unroll
        for (int s = 0; s < 4; ++s) {
            int col = (w*4 + tt)*16 + (lane & 15);
            int off = col*DIM + 32*s + (lane >> 4)*8;
            bh[tt][s] = *(const bf16x8*)&Mh[off];
            bl[tt][s] = *(const bf16x8*)&Ml[off];
        }

    for (int strip = blockIdx.x; strip < NALL/32; strip += gridDim.x) {
        const int sbase = strip * 32;
        __syncthreads();   // prev strip's LDS reads done
        // stage + convert A: 32 rows x 128 cols fp32 -> bf16 hi/lo
        const float4* x4 = (const float4*)x;
        #pragma unroll
        for (int i = 0; i < 4; ++i) {
            int idx = i*256 + tid;          // 0..1023 float4s
            int row = idx >> 5, c4 = idx & 31;
            float4 v = x4[(size_t)(sbase + row)*32 + c4];
            ushort4 hh, ll;
            float f; unsigned short h;
            f = v.x; h = bf16_rne(f); hh.x = h; ll.x = bf16_rne(f - bf16_to_f(h));
            f = v.y; h = bf16_rne(f); hh.y = h; ll.y = bf16_rne(f - bf16_to_f(h));
            f = v.z; h = bf16_rne(f); hh.z = h; ll.z = bf16_rne(f - bf16_to_f(h));
            f = v.w; h = bf16_rne(f); hh.w = h; ll.w = bf16_rne(f - bf16_to_f(h));
            *(ushort4*)&AhL[row][c4*4] = hh;
            *(ushort4*)&AlL[row][c4*4] = ll;
        }
        __syncthreads();

        f32x4 acc[2][4];
        #pragma unroll
        for (int rt = 0; rt < 2; ++rt)
            #pragma unroll
            for (int tt = 0; tt < 4; ++tt)
                acc[rt][tt] = (f32x4){0.f, 0.f, 0.f, 0.f};

        #pragma unroll
        for (int s = 0; s < 4; ++s) {
            bf16x8 ah[2], al[2];
            #pragma unroll
            for (int rt = 0; rt < 2; ++rt) {
                int r = (lane & 15) + 16*rt;
                int kc = 32*s + (lane >> 4)*8;
                ah[rt] = *(const bf16x8*)&AhL[r][kc];
                al[rt] = *(const bf16x8*)&AlL[r][kc];
            }
            #pragma unroll
            for (int rt = 0; rt < 2; ++rt)
                #pragma unroll
                for (int tt = 0; tt < 4; ++tt) {
                    acc[rt][tt] = __builtin_amdgcn_mfma_f32_16x16x32_bf16(ah[rt], bh[tt][s], acc[rt][tt], 0, 0, 0);
                    acc[rt][tt] = __builtin_amdgcn_mfma_f32_16x16x32_bf16(ah[rt], bl[tt][s], acc[rt][tt], 0, 0, 0);
                    acc[rt][tt] = __builtin_amdgcn_mfma_f32_16x16x32_bf16(al[rt], bh[tt][s], acc[rt][tt], 0, 0, 0);
                }
        }

        // store: D row = (lane>>4)*4 + reg, col = lane&15 (within tile)
        #pragma unroll
        for (int rt = 0; rt < 2; ++rt)
            #pragma unroll
            for (int tt = 0; tt < 4; ++tt)
                #pragma unroll
                for (int reg = 0; reg < 4; ++reg) {
                    int row = sbase + rt*16 + (lane >> 4)*4 + reg;
                    int col = w*64 + tt*16 + (lane & 15);
                    outp[(size_t)row*K + col] = acc[rt][tt][reg];
                }
    }
}

extern "C" void kernel_launch(void* const* d_in, const int* in_sizes, int n_in,
                              void* d_out, int out_size, void* d_ws, size_t ws_size,
                              hipStream_t stream)
{
    const float* x = (const float*)d_in[0];   // [8][32768][128]
    const float* W = (const float*)d_in[1];   // [256][256]
    float* outp        = (float*)d_out;                       // [262144][256]
    float* out_centers = outp + (size_t)NALL * K;             // [256][128]

    // workspace layout (4B units)
    float* ws       = (float*)d_ws;
    float* centers  = ws;                              // 32768
    int*   assignv  = (int*)(ws + 32768);              // 32768
    float* sums     = ws + 65536;                      // 32768
    int*   counts   = (int*)(ws + 98304);              // 131072
    int*   chunkoff = (int*)(ws + 229376);             // 131072
    int*   order    = (int*)(ws + 360448);             // 32768
    int*   startk   = (int*)(ws + 393216);             // 256
    int*   cntk     = (int*)(ws + 393472);             // 256
    float* cntf     = ws + 393728;                     // 256
    unsigned short* Mh = (unsigned short*)(ws + 393984);  // 32768 ushort
    unsigned short* Ml = (unsigned short*)(ws + 410368);  // 32768 ushort
    (void)ws_size;

    k_init<<<128, 256, 0, stream>>>(x, centers);
    for (int it = 0; it < ITERS; ++it) {
        k_assign <<<NPTS/128, 256, 0, stream>>>(x, centers, assignv, counts);
        s_offset <<<1, 1024, 0, stream>>>(counts, chunkoff, startk, cntk, cntf);
        s_scatter<<<NCHUNK/4, 256, 0, stream>>>(assignv, chunkoff, order);
        s_fold   <<<K, 128, 0, stream>>>(x, order, startk, cntk, sums);
        s_update <<<128, 256, 0, stream>>>(sums, cntf, centers);
    }
    k_makeM<<<K, DIM, 0, stream>>>(W, centers, Mh, Ml, out_centers);
    k_out_mfma<<<2048, 256, 0, stream>>>(x, Mh, Ml, outp);
}

// Round 8
// 1031.634 us; speedup vs baseline: 2.9383x; 1.5031x over previous
//
#include <hip/hip_runtime.h>

#define DIM    128
#define K      256
#define NPTS   32768
#define NALL   (8*32768)
#define ITERS  10
#define FT     64             // fold pipeline tile

typedef short bf16x8 __attribute__((ext_vector_type(8)));
typedef float f32x4  __attribute__((ext_vector_type(4)));

// fp32 -> bf16 RNE (bit trick), returns ushort
__device__ __forceinline__ unsigned short bf16_rne(float f) {
    unsigned int u = __float_as_uint(f);
    unsigned int r = u + 0x7fffu + ((u >> 16) & 1u);
    return (unsigned short)(r >> 16);
}
__device__ __forceinline__ float bf16_to_f(unsigned short h) {
    return __uint_as_float(((unsigned int)h) << 16);
}

// numpy pairwise sum of squares, n=128, SSE2 path:
//   c[j] = sq[j] + sq[8+j] + ... + sq[120+j]  (ascending, j=0..7)
//   v_l  = c_l + c_{l+4};  res = (v0 + v2) + (v1 + v3)
__device__ __forceinline__ float np_sumsq128(const float* p, int stride) {
    #pragma clang fp contract(off)
    float c[8];
    #pragma unroll
    for (int j = 0; j < 8; ++j) { float x = p[j*stride]; c[j] = x*x; }
    #pragma unroll
    for (int t = 1; t < 16; ++t)
        #pragma unroll
        for (int j = 0; j < 8; ++j) { float x = p[(8*t+j)*stride]; c[j] = c[j] + x*x; }
    float v0 = c[0] + c[4];
    float v1 = c[1] + c[5];
    float v2 = c[2] + c[6];
    float v3 = c[3] + c[7];
    return (v0 + v2) + (v1 + v3);
}

// ---------------- init: centers = X0[:256] ----------------
__global__ void k_init(const float* __restrict__ x0, float* __restrict__ centers) {
    int i = blockIdx.x * blockDim.x + threadIdx.x;
    if (i < K*DIM) centers[i] = x0[i];
}

// ---------------- assignment: bit-replication of np d2 + argmin ----------------
// d2 = fl(fl(x_sq + c_sq) - fl(2*dot)), dot = ascending-k fp32 FMA chain (BLAS).
// grid 256 blocks x 256 thr; block = 128 points (4 passes x 4 waves x 8 points)
__global__ __launch_bounds__(256, 1) void k_assign(
    const float* __restrict__ x0, const float* __restrict__ centers,
    int* __restrict__ assignv)
{
    __shared__ float cT[DIM][K+4];     // centers transposed, +4 pad
    __shared__ float xT[4][DIM][8];    // per-wave 8-point x tile
    __shared__ float csq[K];
    __shared__ float xsq[4][8];

    const int tid  = threadIdx.x;
    const int lane = tid & 63;
    const int w    = tid >> 6;

    for (int idx = tid; idx < K*DIM; idx += 256) {
        int d = idx & (DIM-1);
        int kk = idx >> 7;
        cT[d][kk] = centers[idx];       // idx == kk*128+d (coalesced)
    }
    __syncthreads();
    csq[tid] = np_sumsq128(&cT[0][tid], K+4);
    __syncthreads();

    const float4 cs4 = *(const float4*)&csq[4*lane];

    const int block_base = blockIdx.x * 128;
    for (int pass = 0; pass < 4; ++pass) {
        const int base = block_base + pass*32 + w*8;
        #pragma unroll
        for (int j = 0; j < 4; ++j) {
            int f4 = lane + 64*j;
            int p = f4 & 7, dblk = f4 >> 3;
            float4 v = *(const float4*)&x0[(size_t)(base+p)*DIM + 4*dblk];
            xT[w][4*dblk+0][p] = v.x;
            xT[w][4*dblk+1][p] = v.y;
            xT[w][4*dblk+2][p] = v.z;
            xT[w][4*dblk+3][p] = v.w;
        }
        __syncthreads();

        if (lane < 8) xsq[w][lane] = np_sumsq128(&xT[w][0][lane], 8);
        __syncthreads();

        float acc[8][4];
        #pragma unroll
        for (int p = 0; p < 8; ++p)
            #pragma unroll
            for (int j = 0; j < 4; ++j) acc[p][j] = 0.f;

        // ascending-d fp32 FMA chains == BLAS sgemm per-element order
        for (int d = 0; d < DIM; ++d) {
            const float4 c  = *(const float4*)&cT[d][4*lane];
            const float4 xa = *(const float4*)&xT[w][d][0];
            const float4 xb = *(const float4*)&xT[w][d][4];
            const float xs[8] = {xa.x,xa.y,xa.z,xa.w,xb.x,xb.y,xb.z,xb.w};
            const float cc[4] = {c.x,c.y,c.z,c.w};
            #pragma unroll
            for (int p = 0; p < 8; ++p)
                #pragma unroll
                for (int j = 0; j < 4; ++j)
                    acc[p][j] = fmaf(xs[p], cc[j], acc[p][j]);
        }

        #pragma unroll
        for (int p = 0; p < 8; ++p) {
            #pragma clang fp contract(off)
            const float xs_ = xsq[w][p];
            float bv; int bi;
            { float m = 2.f*acc[p][0]; float t = xs_ + cs4.x; bv = t - m; bi = 4*lane; }
            { float m = 2.f*acc[p][1]; float t = xs_ + cs4.y; float v = t - m; if (v < bv) { bv=v; bi=4*lane+1; } }
            { float m = 2.f*acc[p][2]; float t = xs_ + cs4.z; float v = t - m; if (v < bv) { bv=v; bi=4*lane+2; } }
            { float m = 2.f*acc[p][3]; float t = xs_ + cs4.w; float v = t - m; if (v < bv) { bv=v; bi=4*lane+3; } }
            #pragma unroll
            for (int off = 32; off > 0; off >>= 1) {
                float ov = __shfl_xor(bv, off);
                int   oi = __shfl_xor(bi, off);
                if (ov < bv || (ov == bv && oi < bi)) { bv = ov; bi = oi; }
            }
            if (lane == p) assignv[base + p] = bi;   // first-min tie rule == np.argmin
        }
        __syncthreads();
    }
}

// ---------------- fused segment-sum + update: one block per cluster ----------------
// Block k: compact ascending-n list of points with assign==k into LDS, then
// exact np.add.at replication (ascending-n fp32 left-fold) + counts>0 update.
#define LOADL(vv, t0) do {                                                  \
    int base_ = (t0)*FT;                                                    \
    int nn_[FT];                                                            \
    _Pragma("unroll")                                                       \
    for (int j = 0; j < FT; ++j) {                                          \
        int idx_ = base_ + j;                                               \
        nn_[j] = nlist[idx_ < L ? idx_ : 0];                                \
    }                                                                       \
    _Pragma("unroll")                                                       \
    for (int j = 0; j < FT; ++j) vv[j] = x0[(size_t)nn_[j]*DIM + d];        \
} while (0)

#define FOLDL(vv, t0) do {                                                  \
    int rem_ = L - (t0)*FT;                                                 \
    if (rem_ >= FT) {                                                       \
        _Pragma("unroll")                                                   \
        for (int j = 0; j < FT; ++j) s = s + vv[j];                         \
    } else if (rem_ > 0) {                                                  \
        _Pragma("unroll")                                                   \
        for (int j = 0; j < FT; ++j) { float t_ = s + vv[j]; s = (j < rem_) ? t_ : s; } \
    }                                                                       \
} while (0)

__global__ __launch_bounds__(128, 1) void k_seg(
    const float* __restrict__ x0, const int* __restrict__ assignv,
    float* __restrict__ centers)
{
    __shared__ int nlist[NPTS];        // 128 KB: ascending point list for this cluster
    __shared__ int tsum[2];
    const int k   = blockIdx.x;
    const int tid = threadIdx.x, lane = tid & 63, w = tid >> 6;

    // pass 1: count matches in my contiguous range n in [tid*256, tid*256+256)
    const int4* a4 = (const int4*)assignv;
    int cnt = 0;
    for (int b = 0; b < 64; b += 8) {
        int4 v[8];
        #pragma unroll
        for (int j = 0; j < 8; ++j) v[j] = a4[tid*64 + b + j];
        #pragma unroll
        for (int j = 0; j < 8; ++j)
            cnt += (v[j].x == k) + (v[j].y == k) + (v[j].z == k) + (v[j].w == k);
    }
    // exclusive prefix over 128 threads (2 waves)
    int incl = cnt;
    #pragma unroll
    for (int off = 1; off < 64; off <<= 1) {
        int o = __shfl_up(incl, off);
        if (lane >= off) incl += o;
    }
    if (lane == 63) tsum[w] = incl;
    __syncthreads();
    int excl = incl - cnt + (w == 1 ? tsum[0] : 0);
    const int L = tsum[0] + tsum[1];

    // pass 2: re-read (L2-hot) and write matching n ascending
    int wpos = excl;
    for (int b = 0; b < 64; b += 8) {
        int4 v[8];
        #pragma unroll
        for (int j = 0; j < 8; ++j) v[j] = a4[tid*64 + b + j];
        #pragma unroll
        for (int j = 0; j < 8; ++j) {
            int n0 = tid*256 + (b+j)*4;
            if (v[j].x == k) nlist[wpos++] = n0;
            if (v[j].y == k) nlist[wpos++] = n0+1;
            if (v[j].z == k) nlist[wpos++] = n0+2;
            if (v[j].w == k) nlist[wpos++] = n0+3;
        }
    }
    __syncthreads();

    if (L > 0) {
        #pragma clang fp contract(off)
        const int d = tid;             // 0..127
        float vA[FT], vB[FT];
        float s = 0.f;
        const int nt = (L + FT - 1) / FT;
        LOADL(vA, 0);
        for (int t = 0; t < nt; t += 2) {
            LOADL(vB, t+1);            // in flight while A folds
            FOLDL(vA, t);
            LOADL(vA, t+2);            // in flight while B folds
            FOLDL(vB, t+1);
        }
        float c = (float)L;
        float nv = s / fmaxf(c, 1.f); // IEEE fp32 divide == np
        centers[k*DIM + d] = nv;       // np.where(counts>0, new, old): write only if L>0
    }
}

// ---------------- M = W @ centers / 128 (fp32), split to bf16 hi/lo ----------------
__global__ void k_makeM(const float* __restrict__ W, const float* __restrict__ centers,
                        unsigned short* __restrict__ Mh, unsigned short* __restrict__ Ml,
                        float* __restrict__ out_centers)
{
    int k = blockIdx.x, d = threadIdx.x;
    float s = 0.f;
    #pragma unroll 8
    for (int i = 0; i < K; ++i) s = fmaf(W[k*K + i], centers[i*DIM + d], s);
    s *= (1.f/128.f);
    unsigned short h = bf16_rne(s);
    float lo = s - bf16_to_f(h);
    unsigned short l2 = bf16_rne(lo);
    Mh[k*DIM + d] = h;
    Ml[k*DIM + d] = l2;
    out_centers[k*DIM + d] = centers[k*DIM + d];
}

// ---------------- out = X @ M^T via bf16-split MFMA ----------------
// block = 256 thr (4 waves); wave w owns cols [64w, 64w+64) (4 col-tiles).
// strip = 32 rows; grid-stride over 8192 strips. B (Mh/Ml frags) in registers.
__global__ __launch_bounds__(256, 2) void k_out_mfma(
    const float* __restrict__ x, const unsigned short* __restrict__ Mh,
    const unsigned short* __restrict__ Ml, float* __restrict__ outp)
{
    __shared__ unsigned short AhL[32][DIM+8];
    __shared__ unsigned short AlL[32][DIM+8];

    const int tid = threadIdx.x, lane = tid & 63, w = tid >> 6;

    // B fragments: bh/bl[tt][s], tile tt -> cols 64w+16tt.., kstep s -> k 32s..
    bf16x8 bh[4][4], bl[4][4];
    #pragma unroll
    for (int tt = 0; tt < 4; ++tt)
        #pragma unroll
        for (int s = 0; s < 4; ++s) {
            int col = (w*4 + tt)*16 + (lane & 15);
            int off = col*DIM + 32*s + (lane >> 4)*8;
            bh[tt][s] = *(const bf16x8*)&Mh[off];
            bl[tt][s] = *(const bf16x8*)&Ml[off];
        }

    for (int strip = blockIdx.x; strip < NALL/32; strip += gridDim.x) {
        const int sbase = strip * 32;
        __syncthreads();   // prev strip's LDS reads done
        // stage + convert A: 32 rows x 128 cols fp32 -> bf16 hi/lo
        const float4* x4 = (const float4*)x;
        #pragma unroll
        for (int i = 0; i < 4; ++i) {
            int idx = i*256 + tid;          // 0..1023 float4s
            int row = idx >> 5, c4 = idx & 31;
            float4 v = x4[(size_t)(sbase + row)*32 + c4];
            ushort4 hh, ll;
            float f; unsigned short h;
            f = v.x; h = bf16_rne(f); hh.x = h; ll.x = bf16_rne(f - bf16_to_f(h));
            f = v.y; h = bf16_rne(f); hh.y = h; ll.y = bf16_rne(f - bf16_to_f(h));
            f = v.z; h = bf16_rne(f); hh.z = h; ll.z = bf16_rne(f - bf16_to_f(h));
            f = v.w; h = bf16_rne(f); hh.w = h; ll.w = bf16_rne(f - bf16_to_f(h));
            *(ushort4*)&AhL[row][c4*4] = hh;
            *(ushort4*)&AlL[row][c4*4] = ll;
        }
        __syncthreads();

        f32x4 acc[2][4];
        #pragma unroll
        for (int rt = 0; rt < 2; ++rt)
            #pragma unroll
            for (int tt = 0; tt < 4; ++tt)
                acc[rt][tt] = (f32x4){0.f, 0.f, 0.f, 0.f};

        #pragma unroll
        for (int s = 0; s < 4; ++s) {
            bf16x8 ah[2], al[2];
            #pragma unroll
            for (int rt = 0; rt < 2; ++rt) {
                int r = (lane & 15) + 16*rt;
                int kc = 32*s + (lane >> 4)*8;
                ah[rt] = *(const bf16x8*)&AhL[r][kc];
                al[rt] = *(const bf16x8*)&AlL[r][kc];
            }
            #pragma unroll
            for (int rt = 0; rt < 2; ++rt)
                #pragma unroll
                for (int tt = 0; tt < 4; ++tt) {
                    acc[rt][tt] = __builtin_amdgcn_mfma_f32_16x16x32_bf16(ah[rt], bh[tt][s], acc[rt][tt], 0, 0, 0);
                    acc[rt][tt] = __builtin_amdgcn_mfma_f32_16x16x32_bf16(ah[rt], bl[tt][s], acc[rt][tt], 0, 0, 0);
                    acc[rt][tt] = __builtin_amdgcn_mfma_f32_16x16x32_bf16(al[rt], bh[tt][s], acc[rt][tt], 0, 0, 0);
                }
        }

        // store: D row = (lane>>4)*4 + reg, col = lane&15 (within tile)
        #pragma unroll
        for (int rt = 0; rt < 2; ++rt)
            #pragma unroll
            for (int tt = 0; tt < 4; ++tt)
                #pragma unroll
                for (int reg = 0; reg < 4; ++reg) {
                    int row = sbase + rt*16 + (lane >> 4)*4 + reg;
                    int col = w*64 + tt*16 + (lane & 15);
                    outp[(size_t)row*K + col] = acc[rt][tt][reg];
                }
    }
}

extern "C" void kernel_launch(void* const* d_in, const int* in_sizes, int n_in,
                              void* d_out, int out_size, void* d_ws, size_t ws_size,
                              hipStream_t stream)
{
    const float* x = (const float*)d_in[0];   // [8][32768][128]
    const float* W = (const float*)d_in[1];   // [256][256]
    float* outp        = (float*)d_out;                       // [262144][256]
    float* out_centers = outp + (size_t)NALL * K;             // [256][128]

    // workspace layout (4B units)
    float* ws       = (float*)d_ws;
    float* centers  = ws;                              // 32768
    int*   assignv  = (int*)(ws + 32768);              // 32768
    unsigned short* Mh = (unsigned short*)(ws + 65536);   // 32768 ushort
    unsigned short* Ml = (unsigned short*)(ws + 81920);   // 32768 ushort
    (void)ws_size;

    k_init<<<128, 256, 0, stream>>>(x, centers);
    for (int it = 0; it < ITERS; ++it) {
        k_assign<<<NPTS/128, 256, 0, stream>>>(x, centers, assignv);
        k_seg   <<<K, 128, 0, stream>>>(x, assignv, centers);
    }
    k_makeM<<<K, DIM, 0, stream>>>(W, centers, Mh, Ml, out_centers);
    k_out_mfma<<<2048, 256, 0, stream>>>(x, Mh, Ml, outp);
}